// Round 1
// baseline (790.561 us; speedup 1.0000x reference)
//
#include <hip/hip_runtime.h>

#define NG    32768
#define NN    128
#define NE    1024
#define NK    32
#define ND    3
#define NB    (NG / 2)

// LDS layout sizes
#define XSZ   (NN * ND)        // 384 floats per graph

__global__ __launch_bounds__(256) void dcnn_fused_kernel(
    const float* __restrict__ x,      // (G, N, D)
    const int*   __restrict__ esrc,   // (G, E)
    const int*   __restrict__ edst,   // (G, E)
    const float* __restrict__ extx,   // (G, K, D)
    const float* __restrict__ W,      // (D, D)
    const float* __restrict__ M,      // (D, D)
    const float* __restrict__ U,      // (D, D)
    const float* __restrict__ V,      // (D, D)
    const float* __restrict__ W1,     // (2D, D)
    const float* __restrict__ b1,     // (D,)
    const float* __restrict__ W2,     // (D, 2)
    const float* __restrict__ b2,     // (2,)
    float* __restrict__ out)          // (B, 2)
{
    __shared__ float xl[2 * XSZ];     // x for both graphs      (768)
    __shared__ float agg[2 * XSZ];    // neighbor sums          (768)
    __shared__ float ebuf[2 * NK * ND]; // ext_x rows           (192)
    __shared__ float sred[6];         // per-graph h-sum (D=3 each)
    __shared__ float wb[65];          // all weights: W M U V W1 b1 W2 b2

    const int t  = threadIdx.x;
    const int b  = blockIdx.x;
    const int g0 = b;
    const int g1 = b + NB;

    // ---- Phase A: stage everything into LDS / registers -------------------
    // x tiles, float4-coalesced: 2*384 floats = 192 float4
    if (t < 96) {
        float4 v = ((const float4*)(x + (size_t)g0 * XSZ))[t];
        *(float4*)&xl[t * 4] = v;
    } else if (t < 192) {
        float4 v = ((const float4*)(x + (size_t)g1 * XSZ))[t - 96];
        *(float4*)&xl[XSZ + (t - 96) * 4] = v;
    }

    // edge lists into registers (int4 = 4 edges/thread/graph/array; 256*4 = 1024)
    const int4 rs0 = ((const int4*)(esrc + (size_t)g0 * NE))[t];
    const int4 rd0 = ((const int4*)(edst + (size_t)g0 * NE))[t];
    const int4 rs1 = ((const int4*)(esrc + (size_t)g1 * NE))[t];
    const int4 rd1 = ((const int4*)(edst + (size_t)g1 * NE))[t];

    // ext_x rows, coalesced scalar (96 floats each)
    if (t < 96) {
        ebuf[t] = extx[(size_t)g0 * (NK * ND) + t];
    } else if (t < 192) {
        ebuf[t] = extx[(size_t)g1 * (NK * ND) + (t - 96)];
    }

    // weights -> LDS: W[0:9) M[9:18) U[18:27) V[27:36) W1[36:54) b1[54:57) W2[57:63) b2[63:65)
    if (t < 65) {
        float wv;
        if      (t <  9) wv = W [t];
        else if (t < 18) wv = M [t - 9];
        else if (t < 27) wv = U [t - 18];
        else if (t < 36) wv = V [t - 27];
        else if (t < 54) wv = W1[t - 36];
        else if (t < 57) wv = b1[t - 54];
        else if (t < 63) wv = W2[t - 57];
        else             wv = b2[t - 63];
        wb[t] = wv;
    }

    // zero agg (768 = 3*256) and sred
    agg[t]       = 0.0f;
    agg[t + 256] = 0.0f;
    agg[t + 512] = 0.0f;
    if (t < 6) sred[t] = 0.0f;

    __syncthreads();

    // ---- Phase B: edge scatter-add into LDS agg ---------------------------
    #define SCAT(S, DD, BASE)                                        \
        {                                                            \
            const int sb = (BASE) + (S) * 3;                         \
            const int db = (BASE) + (DD) * 3;                        \
            const float v0 = xl[sb], v1 = xl[sb + 1], v2 = xl[sb + 2]; \
            atomicAdd(&agg[db    ], v0);                             \
            atomicAdd(&agg[db + 1], v1);                             \
            atomicAdd(&agg[db + 2], v2);                             \
        }

    SCAT(rs0.x, rd0.x, 0)
    SCAT(rs0.y, rd0.y, 0)
    SCAT(rs0.z, rd0.z, 0)
    SCAT(rs0.w, rd0.w, 0)
    SCAT(rs1.x, rd1.x, XSZ)
    SCAT(rs1.y, rd1.y, XSZ)
    SCAT(rs1.z, rd1.z, XSZ)
    SCAT(rs1.w, rd1.w, XSZ)
    #undef SCAT

    __syncthreads();

    // ---- Phase C: per-node h = relu(xW + aggM), reduce over nodes ---------
    {
        const int gi   = t >> 7;        // 0 or 1
        const int n    = t & 127;
        const int base = gi * XSZ + n * 3;
        const float x0 = xl[base], x1 = xl[base + 1], x2 = xl[base + 2];
        const float a0 = agg[base], a1 = agg[base + 1], a2 = agg[base + 2];

        float h0, h1, h2;
        h0 = fmaxf(x0 * wb[0] + x1 * wb[3] + x2 * wb[6] +
                   a0 * wb[9] + a1 * wb[12] + a2 * wb[15], 0.0f);
        h1 = fmaxf(x0 * wb[1] + x1 * wb[4] + x2 * wb[7] +
                   a0 * wb[10] + a1 * wb[13] + a2 * wb[16], 0.0f);
        h2 = fmaxf(x0 * wb[2] + x1 * wb[5] + x2 * wb[8] +
                   a0 * wb[11] + a1 * wb[14] + a2 * wb[17], 0.0f);

        // butterfly reduce across the 64-lane wave
        #pragma unroll
        for (int off = 32; off > 0; off >>= 1) {
            h0 += __shfl_xor(h0, off);
            h1 += __shfl_xor(h1, off);
            h2 += __shfl_xor(h2, off);
        }
        if ((t & 63) == 0) {      // 4 waves total, 2 per graph
            atomicAdd(&sred[gi * 3    ], h0);
            atomicAdd(&sred[gi * 3 + 1], h1);
            atomicAdd(&sred[gi * 3 + 2], h2);
        }
    }

    __syncthreads();

    // ---- Phase D: scalar tail on thread 0 ---------------------------------
    if (t == 0) {
        float ge[2][3];
        #pragma unroll
        for (int gi = 0; gi < 2; ++gi) {
            // emb = softmax(h.sum over nodes)
            const float s0 = sred[gi * 3], s1 = sred[gi * 3 + 1], s2 = sred[gi * 3 + 2];
            const float mx = fmaxf(s0, fmaxf(s1, s2));
            const float e0 = __expf(s0 - mx), e1 = __expf(s1 - mx), e2 = __expf(s2 - mx);
            const float inv = 1.0f / (e0 + e1 + e2);
            const float emb0 = e0 * inv, emb1 = e1 * inv, emb2 = e2 * inv;

            // ext_x.sum(axis=k)
            float es0 = 0.f, es1 = 0.f, es2 = 0.f;
            #pragma unroll
            for (int k = 0; k < NK; ++k) {
                es0 += ebuf[gi * 96 + k * 3];
                es1 += ebuf[gi * 96 + k * 3 + 1];
                es2 += ebuf[gi * 96 + k * 3 + 2];
            }

            // ext = relu(emb@U + es@V); g_emb = softmax(ext)
            float ext[3];
            #pragma unroll
            for (int e = 0; e < 3; ++e) {
                float v = emb0 * wb[18 + e] + emb1 * wb[21 + e] + emb2 * wb[24 + e]
                        + es0  * wb[27 + e] + es1  * wb[30 + e] + es2  * wb[33 + e];
                ext[e] = fmaxf(v, 0.0f);
            }
            const float mx2 = fmaxf(ext[0], fmaxf(ext[1], ext[2]));
            const float f0 = __expf(ext[0] - mx2), f1 = __expf(ext[1] - mx2), f2 = __expf(ext[2] - mx2);
            const float inv2 = 1.0f / (f0 + f1 + f2);
            ge[gi][0] = f0 * inv2; ge[gi][1] = f1 * inv2; ge[gi][2] = f2 * inv2;
        }

        // t = [e1*e2, e1+e2]; hlp = relu(t@W1 + b1); out = softmax(hlp@W2 + b2)
        float tt[6];
        tt[0] = ge[0][0] * ge[1][0]; tt[1] = ge[0][1] * ge[1][1]; tt[2] = ge[0][2] * ge[1][2];
        tt[3] = ge[0][0] + ge[1][0]; tt[4] = ge[0][1] + ge[1][1]; tt[5] = ge[0][2] + ge[1][2];

        float hl[3];
        #pragma unroll
        for (int j = 0; j < 3; ++j) {
            float v = wb[54 + j];                 // b1[j]
            #pragma unroll
            for (int i = 0; i < 6; ++i) v += tt[i] * wb[36 + i * 3 + j];
            hl[j] = fmaxf(v, 0.0f);
        }

        const float l0 = wb[63] + hl[0] * wb[57] + hl[1] * wb[59] + hl[2] * wb[61];
        const float l1 = wb[64] + hl[0] * wb[58] + hl[1] * wb[60] + hl[2] * wb[62];
        const float mm = fmaxf(l0, l1);
        const float q0 = __expf(l0 - mm), q1 = __expf(l1 - mm);
        const float qi = 1.0f / (q0 + q1);
        out[(size_t)b * 2    ] = q0 * qi;
        out[(size_t)b * 2 + 1] = q1 * qi;
    }
}

extern "C" void kernel_launch(void* const* d_in, const int* in_sizes, int n_in,
                              void* d_out, int out_size, void* d_ws, size_t ws_size,
                              hipStream_t stream) {
    const float* x    = (const float*)d_in[0];
    const int*   esrc = (const int*)  d_in[1];
    const int*   edst = (const int*)  d_in[2];
    const float* extx = (const float*)d_in[3];
    const float* W    = (const float*)d_in[4];
    const float* M    = (const float*)d_in[5];
    const float* U    = (const float*)d_in[6];
    const float* V    = (const float*)d_in[7];
    const float* W1   = (const float*)d_in[8];
    const float* b1   = (const float*)d_in[9];
    const float* W2   = (const float*)d_in[10];
    const float* b2   = (const float*)d_in[11];
    float* out = (float*)d_out;

    dcnn_fused_kernel<<<NB, 256, 0, stream>>>(
        x, esrc, edst, extx, W, M, U, V, W1, b1, W2, b2, out);
}

// Round 2
// 788.972 us; speedup vs baseline: 1.0020x; 1.0020x over previous
//
#include <hip/hip_runtime.h>

#define NG    32768
#define NN    128
#define NE    1024
#define NK    32
#define ND    3
#define NB    (NG / 2)

// LDS layout sizes
#define XSZ   (NN * ND)        // 384 floats per graph

__global__ __launch_bounds__(256) void dcnn_fused_kernel(
    const float* __restrict__ x,      // (G, N, D)
    const int*   __restrict__ esrc,   // (G, E)
    const int*   __restrict__ edst,   // (G, E)
    const float* __restrict__ extx,   // (G, K, D)
    const float* __restrict__ W,      // (D, D)
    const float* __restrict__ M,      // (D, D)
    const float* __restrict__ U,      // (D, D)
    const float* __restrict__ V,      // (D, D)
    const float* __restrict__ W1,     // (2D, D)
    const float* __restrict__ b1,     // (D,)
    const float* __restrict__ W2,     // (D, 2)
    const float* __restrict__ b2,     // (2,)
    float* __restrict__ out)          // (B, 2)
{
    __shared__ float xl[2 * XSZ];     // x for both graphs      (768)
    __shared__ float agg[2 * XSZ];    // neighbor sums          (768)
    __shared__ float ebuf[2 * NK * ND]; // ext_x rows           (192)
    __shared__ float sred[6];         // per-graph h-sum (D=3 each)
    __shared__ float wb[65];          // all weights: W M U V W1 b1 W2 b2

    const int t  = threadIdx.x;
    const int b  = blockIdx.x;
    const int g0 = b;
    const int g1 = b + NB;

    // ---- Phase A: stage everything into LDS / registers -------------------
    // x tiles, float4-coalesced: 2*384 floats = 192 float4
    if (t < 96) {
        float4 v = ((const float4*)(x + (size_t)g0 * XSZ))[t];
        *(float4*)&xl[t * 4] = v;
    } else if (t < 192) {
        float4 v = ((const float4*)(x + (size_t)g1 * XSZ))[t - 96];
        *(float4*)&xl[XSZ + (t - 96) * 4] = v;
    }

    // edge lists into registers (int4 = 4 edges/thread/graph/array; 256*4 = 1024)
    const int4 rs0 = ((const int4*)(esrc + (size_t)g0 * NE))[t];
    const int4 rd0 = ((const int4*)(edst + (size_t)g0 * NE))[t];
    const int4 rs1 = ((const int4*)(esrc + (size_t)g1 * NE))[t];
    const int4 rd1 = ((const int4*)(edst + (size_t)g1 * NE))[t];

    // ext_x rows, coalesced scalar (96 floats each)
    if (t < 96) {
        ebuf[t] = extx[(size_t)g0 * (NK * ND) + t];
    } else if (t < 192) {
        ebuf[t] = extx[(size_t)g1 * (NK * ND) + (t - 96)];
    }

    // weights -> LDS: W[0:9) M[9:18) U[18:27) V[27:36) W1[36:54) b1[54:57) W2[57:63) b2[63:65)
    if (t < 65) {
        float wv;
        if      (t <  9) wv = W [t];
        else if (t < 18) wv = M [t - 9];
        else if (t < 27) wv = U [t - 18];
        else if (t < 36) wv = V [t - 27];
        else if (t < 54) wv = W1[t - 36];
        else if (t < 57) wv = b1[t - 54];
        else if (t < 63) wv = W2[t - 57];
        else             wv = b2[t - 63];
        wb[t] = wv;
    }

    // zero agg (768 = 3*256) and sred
    agg[t]       = 0.0f;
    agg[t + 256] = 0.0f;
    agg[t + 512] = 0.0f;
    if (t < 6) sred[t] = 0.0f;

    __syncthreads();

    // ---- Phase B: edge scatter-add into LDS agg ---------------------------
    // unsafeAtomicAdd -> native ds_add_f32 (no CAS retry loop).
    #define SCAT(S, DD, BASE)                                        \
        {                                                            \
            const int sb = (BASE) + (S) * 3;                         \
            const int db = (BASE) + (DD) * 3;                        \
            const float v0 = xl[sb], v1 = xl[sb + 1], v2 = xl[sb + 2]; \
            unsafeAtomicAdd(&agg[db    ], v0);                       \
            unsafeAtomicAdd(&agg[db + 1], v1);                       \
            unsafeAtomicAdd(&agg[db + 2], v2);                       \
        }

    SCAT(rs0.x, rd0.x, 0)
    SCAT(rs0.y, rd0.y, 0)
    SCAT(rs0.z, rd0.z, 0)
    SCAT(rs0.w, rd0.w, 0)
    SCAT(rs1.x, rd1.x, XSZ)
    SCAT(rs1.y, rd1.y, XSZ)
    SCAT(rs1.z, rd1.z, XSZ)
    SCAT(rs1.w, rd1.w, XSZ)
    #undef SCAT

    __syncthreads();

    // ---- Phase C: per-node h = relu(xW + aggM), reduce over nodes ---------
    {
        const int gi   = t >> 7;        // 0 or 1
        const int n    = t & 127;
        const int base = gi * XSZ + n * 3;
        const float x0 = xl[base], x1 = xl[base + 1], x2 = xl[base + 2];
        const float a0 = agg[base], a1 = agg[base + 1], a2 = agg[base + 2];

        float h0, h1, h2;
        h0 = fmaxf(x0 * wb[0] + x1 * wb[3] + x2 * wb[6] +
                   a0 * wb[9] + a1 * wb[12] + a2 * wb[15], 0.0f);
        h1 = fmaxf(x0 * wb[1] + x1 * wb[4] + x2 * wb[7] +
                   a0 * wb[10] + a1 * wb[13] + a2 * wb[16], 0.0f);
        h2 = fmaxf(x0 * wb[2] + x1 * wb[5] + x2 * wb[8] +
                   a0 * wb[11] + a1 * wb[14] + a2 * wb[17], 0.0f);

        // butterfly reduce across the 64-lane wave
        #pragma unroll
        for (int off = 32; off > 0; off >>= 1) {
            h0 += __shfl_xor(h0, off);
            h1 += __shfl_xor(h1, off);
            h2 += __shfl_xor(h2, off);
        }
        if ((t & 63) == 0) {      // 4 waves total, 2 per graph
            unsafeAtomicAdd(&sred[gi * 3    ], h0);
            unsafeAtomicAdd(&sred[gi * 3 + 1], h1);
            unsafeAtomicAdd(&sred[gi * 3 + 2], h2);
        }
    }

    __syncthreads();

    // ---- Phase D: scalar tail on thread 0 ---------------------------------
    if (t == 0) {
        float ge[2][3];
        #pragma unroll
        for (int gi = 0; gi < 2; ++gi) {
            // emb = softmax(h.sum over nodes)
            const float s0 = sred[gi * 3], s1 = sred[gi * 3 + 1], s2 = sred[gi * 3 + 2];
            const float mx = fmaxf(s0, fmaxf(s1, s2));
            const float e0 = __expf(s0 - mx), e1 = __expf(s1 - mx), e2 = __expf(s2 - mx);
            const float inv = 1.0f / (e0 + e1 + e2);
            const float emb0 = e0 * inv, emb1 = e1 * inv, emb2 = e2 * inv;

            // ext_x.sum(axis=k)
            float es0 = 0.f, es1 = 0.f, es2 = 0.f;
            #pragma unroll
            for (int k = 0; k < NK; ++k) {
                es0 += ebuf[gi * 96 + k * 3];
                es1 += ebuf[gi * 96 + k * 3 + 1];
                es2 += ebuf[gi * 96 + k * 3 + 2];
            }

            // ext = relu(emb@U + es@V); g_emb = softmax(ext)
            float ext[3];
            #pragma unroll
            for (int e = 0; e < 3; ++e) {
                float v = emb0 * wb[18 + e] + emb1 * wb[21 + e] + emb2 * wb[24 + e]
                        + es0  * wb[27 + e] + es1  * wb[30 + e] + es2  * wb[33 + e];
                ext[e] = fmaxf(v, 0.0f);
            }
            const float mx2 = fmaxf(ext[0], fmaxf(ext[1], ext[2]));
            const float f0 = __expf(ext[0] - mx2), f1 = __expf(ext[1] - mx2), f2 = __expf(ext[2] - mx2);
            const float inv2 = 1.0f / (f0 + f1 + f2);
            ge[gi][0] = f0 * inv2; ge[gi][1] = f1 * inv2; ge[gi][2] = f2 * inv2;
        }

        // t = [e1*e2, e1+e2]; hlp = relu(t@W1 + b1); out = softmax(hlp@W2 + b2)
        float tt[6];
        tt[0] = ge[0][0] * ge[1][0]; tt[1] = ge[0][1] * ge[1][1]; tt[2] = ge[0][2] * ge[1][2];
        tt[3] = ge[0][0] + ge[1][0]; tt[4] = ge[0][1] + ge[1][1]; tt[5] = ge[0][2] + ge[1][2];

        float hl[3];
        #pragma unroll
        for (int j = 0; j < 3; ++j) {
            float v = wb[54 + j];                 // b1[j]
            #pragma unroll
            for (int i = 0; i < 6; ++i) v += tt[i] * wb[36 + i * 3 + j];
            hl[j] = fmaxf(v, 0.0f);
        }

        const float l0 = wb[63] + hl[0] * wb[57] + hl[1] * wb[59] + hl[2] * wb[61];
        const float l1 = wb[64] + hl[0] * wb[58] + hl[1] * wb[60] + hl[2] * wb[62];
        const float mm = fmaxf(l0, l1);
        const float q0 = __expf(l0 - mm), q1 = __expf(l1 - mm);
        const float qi = 1.0f / (q0 + q1);
        out[(size_t)b * 2    ] = q0 * qi;
        out[(size_t)b * 2 + 1] = q1 * qi;
    }
}

extern "C" void kernel_launch(void* const* d_in, const int* in_sizes, int n_in,
                              void* d_out, int out_size, void* d_ws, size_t ws_size,
                              hipStream_t stream) {
    const float* x    = (const float*)d_in[0];
    const int*   esrc = (const int*)  d_in[1];
    const int*   edst = (const int*)  d_in[2];
    const float* extx = (const float*)d_in[3];
    const float* W    = (const float*)d_in[4];
    const float* M    = (const float*)d_in[5];
    const float* U    = (const float*)d_in[6];
    const float* V    = (const float*)d_in[7];
    const float* W1   = (const float*)d_in[8];
    const float* b1   = (const float*)d_in[9];
    const float* W2   = (const float*)d_in[10];
    const float* b2   = (const float*)d_in[11];
    float* out = (float*)d_out;

    dcnn_fused_kernel<<<NB, 256, 0, stream>>>(
        x, esrc, edst, extx, W, M, U, V, W1, b1, W2, b2, out);
}

// Round 3
// 756.968 us; speedup vs baseline: 1.0444x; 1.0423x over previous
//
#include <hip/hip_runtime.h>

#define NG    32768
#define NN    128
#define NE    1024
#define NK    32
#define NB    (NG / 2)
#define XSZ   384          // NN * 3 floats per graph

// Wave-per-graph design: block = 256 threads = 4 waves = 4 graphs = 2 pairs.
// No block barrier until the final pair-combine. All heavy phases are
// wave-synchronous (DS ops execute in order per wave).
__global__ __launch_bounds__(256) void dcnn_wave_kernel(
    const float* __restrict__ x,      // (G, N, 3)
    const int*   __restrict__ esrc,   // (G, E)
    const int*   __restrict__ edst,   // (G, E)
    const float* __restrict__ extx,   // (G, K, 3)
    const float* __restrict__ W,      // (3,3)
    const float* __restrict__ M,      // (3,3)
    const float* __restrict__ U,      // (3,3)
    const float* __restrict__ V,      // (3,3)
    const float* __restrict__ W1,     // (6,3)
    const float* __restrict__ b1,     // (3,)
    const float* __restrict__ W2,     // (3,2)
    const float* __restrict__ b2,     // (2,)
    float* __restrict__ out)          // (B, 2)
{
    __shared__ float xl [4][XSZ];
    __shared__ float agg[4][XSZ];
    __shared__ float ge [4][3];

    const int t    = threadIdx.x;
    const int w    = t >> 6;          // wave id 0..3
    const int lane = t & 63;
    const int pair = blockIdx.x * 2 + (w >> 1);
    const int g    = (w & 1) ? (pair + NB) : pair;

    // ---- stage: x -> LDS (float4), edges -> regs (int4), ext row -> regs --
    const float4* xp = (const float4*)(x + (size_t)g * XSZ);
    float4 v1 = xp[lane];
    float4 v2;
    if (lane < 32) v2 = xp[64 + lane];

    const int4* sp = (const int4*)(esrc + (size_t)g * NE);
    const int4* dp = (const int4*)(edst + (size_t)g * NE);
    const int4 s0 = sp[lane], s1 = sp[lane + 64], s2 = sp[lane + 128], s3 = sp[lane + 192];
    const int4 d0 = dp[lane], d1 = dp[lane + 64], d2 = dp[lane + 128], d3 = dp[lane + 192];

    float er0 = 0.f, er1 = 0.f, er2 = 0.f;
    if (lane < NK) {
        const float* ep = extx + (size_t)g * (NK * 3) + lane * 3;
        er0 = ep[0]; er1 = ep[1]; er2 = ep[2];
    }

    *(float4*)&xl[w][lane * 4] = v1;
    if (lane < 32) *(float4*)&xl[w][256 + lane * 4] = v2;

    // zero agg: 6 floats/lane
    *(float2*)&agg[w][lane * 6    ] = make_float2(0.f, 0.f);
    *(float2*)&agg[w][lane * 6 + 2] = make_float2(0.f, 0.f);
    *(float2*)&agg[w][lane * 6 + 4] = make_float2(0.f, 0.f);

    __builtin_amdgcn_wave_barrier();   // pin compiler ordering (DS in-order per wave)

    // ---- scatter: 16 edges per lane, LDS gather + native ds_add_f32 -------
    #define SCAT(SV, DV)                                                  \
        {                                                                 \
            const int sb = (SV) * 3, db = (DV) * 3;                       \
            const float a0 = xl[w][sb], a1 = xl[w][sb + 1], a2 = xl[w][sb + 2]; \
            unsafeAtomicAdd(&agg[w][db    ], a0);                         \
            unsafeAtomicAdd(&agg[w][db + 1], a1);                         \
            unsafeAtomicAdd(&agg[w][db + 2], a2);                         \
        }
    SCAT(s0.x, d0.x) SCAT(s0.y, d0.y) SCAT(s0.z, d0.z) SCAT(s0.w, d0.w)
    SCAT(s1.x, d1.x) SCAT(s1.y, d1.y) SCAT(s1.z, d1.z) SCAT(s1.w, d1.w)
    SCAT(s2.x, d2.x) SCAT(s2.y, d2.y) SCAT(s2.z, d2.z) SCAT(s2.w, d2.w)
    SCAT(s3.x, d3.x) SCAT(s3.y, d3.y) SCAT(s3.z, d3.z) SCAT(s3.w, d3.w)
    #undef SCAT

    __builtin_amdgcn_wave_barrier();

    // ---- per-node h = relu(xW + aggM); each lane owns nodes lane, lane+64 -
    // Weights at constant indices -> compiler scalarizes to s_load (uniform).
    float h0 = 0.f, h1 = 0.f, h2 = 0.f;
    #pragma unroll
    for (int half = 0; half < 2; ++half) {
        const int base = half * 192 + lane * 3;
        const float x0 = xl[w][base], x1 = xl[w][base + 1], x2 = xl[w][base + 2];
        const float a0 = agg[w][base], a1 = agg[w][base + 1], a2 = agg[w][base + 2];
        h0 += fmaxf(x0 * W[0] + x1 * W[3] + x2 * W[6] +
                    a0 * M[0] + a1 * M[3] + a2 * M[6], 0.f);
        h1 += fmaxf(x0 * W[1] + x1 * W[4] + x2 * W[7] +
                    a0 * M[1] + a1 * M[4] + a2 * M[7], 0.f);
        h2 += fmaxf(x0 * W[2] + x1 * W[5] + x2 * W[8] +
                    a0 * M[2] + a1 * M[5] + a2 * M[8], 0.f);
    }

    // butterfly reduce h-sums and ext-row sums across the 64-lane wave
    #pragma unroll
    for (int off = 32; off > 0; off >>= 1) {
        h0  += __shfl_xor(h0,  off);
        h1  += __shfl_xor(h1,  off);
        h2  += __shfl_xor(h2,  off);
        er0 += __shfl_xor(er0, off);
        er1 += __shfl_xor(er1, off);
        er2 += __shfl_xor(er2, off);
    }

    // ---- per-wave tail on lane 0: emb softmax -> ext MLP -> g_emb ---------
    if (lane == 0) {
        const float mx = fmaxf(h0, fmaxf(h1, h2));
        const float e0 = __expf(h0 - mx), e1 = __expf(h1 - mx), e2 = __expf(h2 - mx);
        const float inv = 1.0f / (e0 + e1 + e2);
        const float emb0 = e0 * inv, emb1 = e1 * inv, emb2 = e2 * inv;

        float ext[3];
        #pragma unroll
        for (int e = 0; e < 3; ++e) {
            const float vv = emb0 * U[e] + emb1 * U[3 + e] + emb2 * U[6 + e]
                           + er0  * V[e] + er1  * V[3 + e] + er2  * V[6 + e];
            ext[e] = fmaxf(vv, 0.f);
        }
        const float mx2 = fmaxf(ext[0], fmaxf(ext[1], ext[2]));
        const float f0 = __expf(ext[0] - mx2), f1 = __expf(ext[1] - mx2), f2 = __expf(ext[2] - mx2);
        const float inv2 = 1.0f / (f0 + f1 + f2);
        ge[w][0] = f0 * inv2; ge[w][1] = f1 * inv2; ge[w][2] = f2 * inv2;
    }

    __syncthreads();   // the single block barrier: pair combine needs both waves

    // ---- pair combine: lane 0 of waves 0 and 2 ----------------------------
    if ((w & 1) == 0 && lane == 0) {
        float tt[6];
        tt[0] = ge[w][0] * ge[w + 1][0];
        tt[1] = ge[w][1] * ge[w + 1][1];
        tt[2] = ge[w][2] * ge[w + 1][2];
        tt[3] = ge[w][0] + ge[w + 1][0];
        tt[4] = ge[w][1] + ge[w + 1][1];
        tt[5] = ge[w][2] + ge[w + 1][2];

        float hl[3];
        #pragma unroll
        for (int j = 0; j < 3; ++j) {
            float vv = b1[j];
            #pragma unroll
            for (int i = 0; i < 6; ++i) vv += tt[i] * W1[i * 3 + j];
            hl[j] = fmaxf(vv, 0.f);
        }

        const float l0 = b2[0] + hl[0] * W2[0] + hl[1] * W2[2] + hl[2] * W2[4];
        const float l1 = b2[1] + hl[0] * W2[1] + hl[1] * W2[3] + hl[2] * W2[5];
        const float mm = fmaxf(l0, l1);
        const float q0 = __expf(l0 - mm), q1 = __expf(l1 - mm);
        const float qi = 1.0f / (q0 + q1);
        out[(size_t)pair * 2    ] = q0 * qi;
        out[(size_t)pair * 2 + 1] = q1 * qi;
    }
}

extern "C" void kernel_launch(void* const* d_in, const int* in_sizes, int n_in,
                              void* d_out, int out_size, void* d_ws, size_t ws_size,
                              hipStream_t stream) {
    const float* x    = (const float*)d_in[0];
    const int*   esrc = (const int*)  d_in[1];
    const int*   edst = (const int*)  d_in[2];
    const float* extx = (const float*)d_in[3];
    const float* W    = (const float*)d_in[4];
    const float* M    = (const float*)d_in[5];
    const float* U    = (const float*)d_in[6];
    const float* V    = (const float*)d_in[7];
    const float* W1   = (const float*)d_in[8];
    const float* b1   = (const float*)d_in[9];
    const float* W2   = (const float*)d_in[10];
    const float* b2   = (const float*)d_in[11];
    float* out = (float*)d_out;

    // 2 pairs per block -> NB/2 blocks
    dcnn_wave_kernel<<<NB / 2, 256, 0, stream>>>(
        x, esrc, edst, extx, W, M, U, V, W1, b1, W2, b2, out);
}

// Round 4
// 747.628 us; speedup vs baseline: 1.0574x; 1.0125x over previous
//
#include <hip/hip_runtime.h>

#define NG    32768
#define NN    128
#define NE    1024
#define NK    32
#define NB    (NG / 2)
#define CPY   400            // replica stride (floats); 400 % 32 = 16 -> bank shift
#define AGW   (2 * CPY)      // per-wave agg region: 2 replicas

// Wave-per-graph. Gather of x[src] comes from GLOBAL (L1/L2-hot) - the DS pipe
// carries only the scatter atomics. agg is replicated 2x per wave (lane parity)
// to halve same-address atomic serialization; replicas are bank-shifted.
__global__ __launch_bounds__(256) void dcnn_wave_kernel(
    const float* __restrict__ x,      // (G, N, 3)
    const int*   __restrict__ esrc,   // (G, E)
    const int*   __restrict__ edst,   // (G, E)
    const float* __restrict__ extx,   // (G, K, 3)
    const float* __restrict__ W,      // (3,3)
    const float* __restrict__ M,      // (3,3)
    const float* __restrict__ U,      // (3,3)
    const float* __restrict__ V,      // (3,3)
    const float* __restrict__ W1,     // (6,3)
    const float* __restrict__ b1,     // (3,)
    const float* __restrict__ W2,     // (3,2)
    const float* __restrict__ b2,     // (2,)
    float* __restrict__ out)          // (B, 2)
{
    __shared__ float agg[4 * AGW];    // 12.5 KB
    __shared__ float ge[4][3];

    const int t    = threadIdx.x;
    const int w    = t >> 6;
    const int lane = t & 63;
    const int pair = blockIdx.x * 2 + (w >> 1);
    const int g    = (w & 1) ? (pair + NB) : pair;

    const float* __restrict__ xg = x + (size_t)g * (NN * 3);

    // ---- edge lists -> registers (coalesced int4) -------------------------
    const int4* sp = (const int4*)(esrc + (size_t)g * NE);
    const int4* dp = (const int4*)(edst + (size_t)g * NE);
    const int4 s0 = sp[lane], s1 = sp[lane + 64], s2 = sp[lane + 128], s3 = sp[lane + 192];
    const int4 d0 = dp[lane], d1 = dp[lane + 64], d2 = dp[lane + 128], d3 = dp[lane + 192];

    // ext row (lanes 0..31)
    float er0 = 0.f, er1 = 0.f, er2 = 0.f;
    if (lane < NK) {
        const float* ep = extx + (size_t)g * (NK * 3) + lane * 3;
        er0 = ep[0]; er1 = ep[1]; er2 = ep[2];
    }

    // ---- zero both agg replicas (800 floats/wave) -------------------------
    float* aw = &agg[w * AGW];
    #pragma unroll
    for (int i = 0; i < 6; ++i)
        *(float2*)&aw[i * 128 + lane * 2] = make_float2(0.f, 0.f);
    if (lane < 16)
        *(float2*)&aw[768 + lane * 2] = make_float2(0.f, 0.f);

    __builtin_amdgcn_wave_barrier();   // DS ops are in-order per wave

    // ---- scatter: gather x[src] from global (L1/L2), ds_add into replica --
    float* ac = aw + (lane & 1) * CPY;
    #define SCAT(SV, DV)                                                   \
        {                                                                  \
            const float* xr = xg + (SV) * 3;                               \
            const float a0 = xr[0], a1 = xr[1], a2 = xr[2];                \
            const int db = (DV) * 3;                                       \
            unsafeAtomicAdd(&ac[db    ], a0);                              \
            unsafeAtomicAdd(&ac[db + 1], a1);                              \
            unsafeAtomicAdd(&ac[db + 2], a2);                              \
        }
    SCAT(s0.x, d0.x) SCAT(s0.y, d0.y) SCAT(s0.z, d0.z) SCAT(s0.w, d0.w)
    SCAT(s1.x, d1.x) SCAT(s1.y, d1.y) SCAT(s1.z, d1.z) SCAT(s1.w, d1.w)
    SCAT(s2.x, d2.x) SCAT(s2.y, d2.y) SCAT(s2.z, d2.z) SCAT(s2.w, d2.w)
    SCAT(s3.x, d3.x) SCAT(s3.y, d3.y) SCAT(s3.z, d3.z) SCAT(s3.w, d3.w)
    #undef SCAT

    __builtin_amdgcn_wave_barrier();

    // ---- per-node h = relu(xW + aggM); lane owns nodes lane, lane+64 ------
    float h0 = 0.f, h1 = 0.f, h2 = 0.f;
    #pragma unroll
    for (int half = 0; half < 2; ++half) {
        const int n = lane + half * 64;
        const float* xr = xg + n * 3;          // L1-hot after gather phase
        const float x0 = xr[0], x1 = xr[1], x2 = xr[2];
        const float a0 = aw[n * 3    ] + aw[CPY + n * 3    ];
        const float a1 = aw[n * 3 + 1] + aw[CPY + n * 3 + 1];
        const float a2 = aw[n * 3 + 2] + aw[CPY + n * 3 + 2];
        h0 += fmaxf(x0 * W[0] + x1 * W[3] + x2 * W[6] +
                    a0 * M[0] + a1 * M[3] + a2 * M[6], 0.f);
        h1 += fmaxf(x0 * W[1] + x1 * W[4] + x2 * W[7] +
                    a0 * M[1] + a1 * M[4] + a2 * M[7], 0.f);
        h2 += fmaxf(x0 * W[2] + x1 * W[5] + x2 * W[8] +
                    a0 * M[2] + a1 * M[5] + a2 * M[8], 0.f);
    }

    // ---- reduce within 32-lane halves, then combine halves via readlane ---
    #pragma unroll
    for (int off = 16; off > 0; off >>= 1) {
        h0  += __shfl_xor(h0,  off);
        h1  += __shfl_xor(h1,  off);
        h2  += __shfl_xor(h2,  off);
        er0 += __shfl_xor(er0, off);
        er1 += __shfl_xor(er1, off);
        er2 += __shfl_xor(er2, off);
    }

    #define RL(v) (__uint_as_float(__builtin_amdgcn_readlane(__float_as_uint(v), 0)) + \
                   __uint_as_float(__builtin_amdgcn_readlane(__float_as_uint(v), 32)))
    const float H0 = RL(h0), H1 = RL(h1), H2 = RL(h2);
    const float E0 = RL(er0), E1 = RL(er1), E2 = RL(er2);
    #undef RL

    // ---- per-wave tail: emb softmax -> ext MLP -> g_emb -------------------
    if (lane == 0) {
        const float mx = fmaxf(H0, fmaxf(H1, H2));
        const float e0 = __expf(H0 - mx), e1 = __expf(H1 - mx), e2 = __expf(H2 - mx);
        const float inv = 1.0f / (e0 + e1 + e2);
        const float emb0 = e0 * inv, emb1 = e1 * inv, emb2 = e2 * inv;

        float ext[3];
        #pragma unroll
        for (int e = 0; e < 3; ++e) {
            const float vv = emb0 * U[e] + emb1 * U[3 + e] + emb2 * U[6 + e]
                           + E0   * V[e] + E1   * V[3 + e] + E2   * V[6 + e];
            ext[e] = fmaxf(vv, 0.f);
        }
        const float mx2 = fmaxf(ext[0], fmaxf(ext[1], ext[2]));
        const float f0 = __expf(ext[0] - mx2), f1 = __expf(ext[1] - mx2), f2 = __expf(ext[2] - mx2);
        const float inv2 = 1.0f / (f0 + f1 + f2);
        ge[w][0] = f0 * inv2; ge[w][1] = f1 * inv2; ge[w][2] = f2 * inv2;
    }

    __syncthreads();

    // ---- pair combine on lane 0 of waves 0 and 2 --------------------------
    if ((w & 1) == 0 && lane == 0) {
        float tt[6];
        tt[0] = ge[w][0] * ge[w + 1][0];
        tt[1] = ge[w][1] * ge[w + 1][1];
        tt[2] = ge[w][2] * ge[w + 1][2];
        tt[3] = ge[w][0] + ge[w + 1][0];
        tt[4] = ge[w][1] + ge[w + 1][1];
        tt[5] = ge[w][2] + ge[w + 1][2];

        float hl[3];
        #pragma unroll
        for (int j = 0; j < 3; ++j) {
            float vv = b1[j];
            #pragma unroll
            for (int i = 0; i < 6; ++i) vv += tt[i] * W1[i * 3 + j];
            hl[j] = fmaxf(vv, 0.f);
        }

        const float l0 = b2[0] + hl[0] * W2[0] + hl[1] * W2[2] + hl[2] * W2[4];
        const float l1 = b2[1] + hl[0] * W2[1] + hl[1] * W2[3] + hl[2] * W2[5];
        const float mm = fmaxf(l0, l1);
        const float q0 = __expf(l0 - mm), q1 = __expf(l1 - mm);
        const float qi = 1.0f / (q0 + q1);
        out[(size_t)pair * 2    ] = q0 * qi;
        out[(size_t)pair * 2 + 1] = q1 * qi;
    }
}

extern "C" void kernel_launch(void* const* d_in, const int* in_sizes, int n_in,
                              void* d_out, int out_size, void* d_ws, size_t ws_size,
                              hipStream_t stream) {
    const float* x    = (const float*)d_in[0];
    const int*   esrc = (const int*)  d_in[1];
    const int*   edst = (const int*)  d_in[2];
    const float* extx = (const float*)d_in[3];
    const float* W    = (const float*)d_in[4];
    const float* M    = (const float*)d_in[5];
    const float* U    = (const float*)d_in[6];
    const float* V    = (const float*)d_in[7];
    const float* W1   = (const float*)d_in[8];
    const float* b1   = (const float*)d_in[9];
    const float* W2   = (const float*)d_in[10];
    const float* b2   = (const float*)d_in[11];
    float* out = (float*)d_out;

    dcnn_wave_kernel<<<NB / 2, 256, 0, stream>>>(
        x, esrc, edst, extx, W, M, U, V, W1, b1, W2, b2, out);
}

// Round 5
// 393.972 us; speedup vs baseline: 2.0066x; 1.8977x over previous
//
#include <hip/hip_runtime.h>

#define NG    32768
#define NN    128
#define NE    1024
#define NK    32
#define NB    (NG / 2)
#define RSTR  17                 // A row stride in dwords (odd -> conflict-free)
#define AWDW  (NN * RSTR)        // 2176 dwords per wave (8.5 KB)

// Wave-per-graph. The neighbor scatter is factored through a dense u4-packed
// adjacency-count matrix A (128x128): build = ONE ds_add_u32 per edge (3x fewer
// atomic lane-ops than scattering 3 floats), then agg = A @ x on the VALU pipe
// with agg staying in registers.
__global__ __launch_bounds__(256) void dcnn_adj_kernel(
    const float* __restrict__ x,      // (G, N, 3)
    const int*   __restrict__ esrc,   // (G, E)
    const int*   __restrict__ edst,   // (G, E)
    const float* __restrict__ extx,   // (G, K, 3)
    const float* __restrict__ W,      // (3,3)
    const float* __restrict__ M,      // (3,3)
    const float* __restrict__ U,      // (3,3)
    const float* __restrict__ V,      // (3,3)
    const float* __restrict__ W1,     // (6,3)
    const float* __restrict__ b1,     // (3,)
    const float* __restrict__ W2,     // (3,2)
    const float* __restrict__ b2,     // (2,)
    float* __restrict__ out)          // (B, 2)
{
    __shared__ unsigned A[4 * AWDW];  // 34.8 KB
    __shared__ float ge[4][3];

    const int t    = threadIdx.x;
    const int w    = t >> 6;
    const int lane = t & 63;
    const int pair = blockIdx.x * 2 + (w >> 1);
    const int g    = (w & 1) ? (pair + NB) : pair;

    const float* __restrict__ xg = x + (size_t)g * (NN * 3);

    // ---- edge lists -> registers (coalesced int4) -------------------------
    const int4* sp = (const int4*)(esrc + (size_t)g * NE);
    const int4* dp = (const int4*)(edst + (size_t)g * NE);
    const int4 s0 = sp[lane], s1 = sp[lane + 64], s2 = sp[lane + 128], s3 = sp[lane + 192];
    const int4 d0 = dp[lane], d1 = dp[lane + 64], d2 = dp[lane + 128], d3 = dp[lane + 192];

    // ext row (lanes 0..31)
    float er0 = 0.f, er1 = 0.f, er2 = 0.f;
    if (lane < NK) {
        const float* ep = extx + (size_t)g * (NK * 3) + lane * 3;
        er0 = ep[0]; er1 = ep[1]; er2 = ep[2];
    }

    // ---- zero A (2176 dwords/wave, conflict-free) -------------------------
    unsigned* Aw = &A[w * AWDW];
    #pragma unroll
    for (int i = 0; i < 34; ++i) {
        const int idx = i * 64 + lane;
        if (idx < AWDW) Aw[idx] = 0u;
    }

    __builtin_amdgcn_wave_barrier();   // DS ops in-order per wave

    // ---- build adjacency counts: ONE ds_add_u32 per edge ------------------
    #define SCAT(SV, DV) \
        atomicAdd(&Aw[(DV) * RSTR + ((SV) >> 3)], 1u << (4 * ((SV) & 7)));
    SCAT(s0.x, d0.x) SCAT(s0.y, d0.y) SCAT(s0.z, d0.z) SCAT(s0.w, d0.w)
    SCAT(s1.x, d1.x) SCAT(s1.y, d1.y) SCAT(s1.z, d1.z) SCAT(s1.w, d1.w)
    SCAT(s2.x, d2.x) SCAT(s2.y, d2.y) SCAT(s2.z, d2.z) SCAT(s2.w, d2.w)
    SCAT(s3.x, d3.x) SCAT(s3.y, d3.y) SCAT(s3.z, d3.z) SCAT(s3.w, d3.w)
    #undef SCAT

    __builtin_amdgcn_wave_barrier();

    // ---- agg = A @ x : lane owns dst rows {lane, lane+64}, agg in regs ----
    float ac0 = 0.f, ac1 = 0.f, ac2 = 0.f;   // node lane
    float ac3 = 0.f, ac4 = 0.f, ac5 = 0.f;   // node lane+64
    const int r0 = lane * RSTR;
    const int r1 = (lane + 64) * RSTR;

    #pragma unroll
    for (int j = 0; j < 16; ++j) {
        const unsigned da = Aw[r0 + j];
        const unsigned db = Aw[r1 + j];
        // x for srcs j*8 .. j*8+7 : 24 floats, same address for all lanes (L1 broadcast)
        float q[24];
        *(float4*)&q[0]  = *(const float4*)(xg + j * 24);
        *(float4*)&q[4]  = *(const float4*)(xg + j * 24 + 4);
        *(float4*)&q[8]  = *(const float4*)(xg + j * 24 + 8);
        *(float4*)&q[12] = *(const float4*)(xg + j * 24 + 12);
        *(float4*)&q[16] = *(const float4*)(xg + j * 24 + 16);
        *(float4*)&q[20] = *(const float4*)(xg + j * 24 + 20);
        #pragma unroll
        for (int o = 0; o < 8; ++o) {
            const float ca = (float)((da >> (4 * o)) & 15u);
            const float cb = (float)((db >> (4 * o)) & 15u);
            const float xs0 = q[o * 3], xs1 = q[o * 3 + 1], xs2 = q[o * 3 + 2];
            ac0 += ca * xs0; ac1 += ca * xs1; ac2 += ca * xs2;
            ac3 += cb * xs0; ac4 += cb * xs1; ac5 += cb * xs2;
        }
    }

    // ---- per-node h = relu(xW + aggM) for the 2 owned nodes ---------------
    float h0, h1, h2;
    {
        const float* xr = xg + lane * 3;
        const float x0 = xr[0], x1 = xr[1], x2 = xr[2];
        h0 = fmaxf(x0 * W[0] + x1 * W[3] + x2 * W[6] +
                   ac0 * M[0] + ac1 * M[3] + ac2 * M[6], 0.f);
        h1 = fmaxf(x0 * W[1] + x1 * W[4] + x2 * W[7] +
                   ac0 * M[1] + ac1 * M[4] + ac2 * M[7], 0.f);
        h2 = fmaxf(x0 * W[2] + x1 * W[5] + x2 * W[8] +
                   ac0 * M[2] + ac1 * M[5] + ac2 * M[8], 0.f);
    }
    {
        const float* xr = xg + (lane + 64) * 3;
        const float x0 = xr[0], x1 = xr[1], x2 = xr[2];
        h0 += fmaxf(x0 * W[0] + x1 * W[3] + x2 * W[6] +
                    ac3 * M[0] + ac4 * M[3] + ac5 * M[6], 0.f);
        h1 += fmaxf(x0 * W[1] + x1 * W[4] + x2 * W[7] +
                    ac3 * M[1] + ac4 * M[4] + ac5 * M[7], 0.f);
        h2 += fmaxf(x0 * W[2] + x1 * W[5] + x2 * W[8] +
                    ac3 * M[2] + ac4 * M[5] + ac5 * M[8], 0.f);
    }

    // ---- reduce within 32-lane halves, combine halves via readlane --------
    #pragma unroll
    for (int off = 16; off > 0; off >>= 1) {
        h0  += __shfl_xor(h0,  off);
        h1  += __shfl_xor(h1,  off);
        h2  += __shfl_xor(h2,  off);
        er0 += __shfl_xor(er0, off);
        er1 += __shfl_xor(er1, off);
        er2 += __shfl_xor(er2, off);
    }
    #define RL(v) (__uint_as_float(__builtin_amdgcn_readlane(__float_as_uint(v), 0)) + \
                   __uint_as_float(__builtin_amdgcn_readlane(__float_as_uint(v), 32)))
    const float H0 = RL(h0), H1 = RL(h1), H2 = RL(h2);
    const float E0 = RL(er0), E1 = RL(er1), E2 = RL(er2);
    #undef RL

    // ---- per-wave tail: emb softmax -> ext MLP -> g_emb -------------------
    if (lane == 0) {
        const float mx = fmaxf(H0, fmaxf(H1, H2));
        const float e0 = __expf(H0 - mx), e1 = __expf(H1 - mx), e2 = __expf(H2 - mx);
        const float inv = 1.0f / (e0 + e1 + e2);
        const float emb0 = e0 * inv, emb1 = e1 * inv, emb2 = e2 * inv;

        float ext[3];
        #pragma unroll
        for (int e = 0; e < 3; ++e) {
            const float vv = emb0 * U[e] + emb1 * U[3 + e] + emb2 * U[6 + e]
                           + E0   * V[e] + E1   * V[3 + e] + E2   * V[6 + e];
            ext[e] = fmaxf(vv, 0.f);
        }
        const float mx2 = fmaxf(ext[0], fmaxf(ext[1], ext[2]));
        const float f0 = __expf(ext[0] - mx2), f1 = __expf(ext[1] - mx2), f2 = __expf(ext[2] - mx2);
        const float inv2 = 1.0f / (f0 + f1 + f2);
        ge[w][0] = f0 * inv2; ge[w][1] = f1 * inv2; ge[w][2] = f2 * inv2;
    }

    __syncthreads();

    // ---- pair combine on lane 0 of waves 0 and 2 --------------------------
    if ((w & 1) == 0 && lane == 0) {
        float tt[6];
        tt[0] = ge[w][0] * ge[w + 1][0];
        tt[1] = ge[w][1] * ge[w + 1][1];
        tt[2] = ge[w][2] * ge[w + 1][2];
        tt[3] = ge[w][0] + ge[w + 1][0];
        tt[4] = ge[w][1] + ge[w + 1][1];
        tt[5] = ge[w][2] + ge[w + 1][2];

        float hl[3];
        #pragma unroll
        for (int j = 0; j < 3; ++j) {
            float vv = b1[j];
            #pragma unroll
            for (int i = 0; i < 6; ++i) vv += tt[i] * W1[i * 3 + j];
            hl[j] = fmaxf(vv, 0.f);
        }

        const float l0 = b2[0] + hl[0] * W2[0] + hl[1] * W2[2] + hl[2] * W2[4];
        const float l1 = b2[1] + hl[0] * W2[1] + hl[1] * W2[3] + hl[2] * W2[5];
        const float mm = fmaxf(l0, l1);
        const float q0 = __expf(l0 - mm), q1 = __expf(l1 - mm);
        const float qi = 1.0f / (q0 + q1);
        out[(size_t)pair * 2    ] = q0 * qi;
        out[(size_t)pair * 2 + 1] = q1 * qi;
    }
}

extern "C" void kernel_launch(void* const* d_in, const int* in_sizes, int n_in,
                              void* d_out, int out_size, void* d_ws, size_t ws_size,
                              hipStream_t stream) {
    const float* x    = (const float*)d_in[0];
    const int*   esrc = (const int*)  d_in[1];
    const int*   edst = (const int*)  d_in[2];
    const float* extx = (const float*)d_in[3];
    const float* W    = (const float*)d_in[4];
    const float* M    = (const float*)d_in[5];
    const float* U    = (const float*)d_in[6];
    const float* V    = (const float*)d_in[7];
    const float* W1   = (const float*)d_in[8];
    const float* b1   = (const float*)d_in[9];
    const float* W2   = (const float*)d_in[10];
    const float* b2   = (const float*)d_in[11];
    float* out = (float*)d_out;

    dcnn_adj_kernel<<<NB / 2, 256, 0, stream>>>(
        x, esrc, edst, extx, W, M, U, V, W1, b1, W2, b2, out);
}

// Round 6
// 392.479 us; speedup vs baseline: 2.0143x; 1.0038x over previous
//
#include <hip/hip_runtime.h>

#define NG    32768
#define NN    128
#define NE    1024
#define NK    32
#define NB    (NG / 2)
#define RSTR  17                 // A row stride in dwords (odd -> conflict-free)
#define AWDW  (NN * RSTR)        // 2176 dwords per wave (8.5 KB)

// Identical to R5 except: the count-build atomic is forced to the no-return
// form `ds_add_u32` via inline asm (probe: is the 211 cyc/instr atomic rate an
// artifact of rtn-form emission?). Explicit lgkmcnt(0) wait afterwards since
// the asm hides the RAW dependency on the A-table from the compiler.
__global__ __launch_bounds__(256) void dcnn_adj_kernel(
    const float* __restrict__ x,      // (G, N, 3)
    const int*   __restrict__ esrc,   // (G, E)
    const int*   __restrict__ edst,   // (G, E)
    const float* __restrict__ extx,   // (G, K, 3)
    const float* __restrict__ W,      // (3,3)
    const float* __restrict__ M,      // (3,3)
    const float* __restrict__ U,      // (3,3)
    const float* __restrict__ V,      // (3,3)
    const float* __restrict__ W1,     // (6,3)
    const float* __restrict__ b1,     // (3,)
    const float* __restrict__ W2,     // (3,2)
    const float* __restrict__ b2,     // (2,)
    float* __restrict__ out)          // (B, 2)
{
    __shared__ unsigned A[4 * AWDW];  // 34.8 KB
    __shared__ float ge[4][3];

    const int t    = threadIdx.x;
    const int w    = t >> 6;
    const int lane = t & 63;
    const int pair = blockIdx.x * 2 + (w >> 1);
    const int g    = (w & 1) ? (pair + NB) : pair;

    const float* __restrict__ xg = x + (size_t)g * (NN * 3);

    // ---- edge lists -> registers (coalesced int4) -------------------------
    const int4* sp = (const int4*)(esrc + (size_t)g * NE);
    const int4* dp = (const int4*)(edst + (size_t)g * NE);
    const int4 s0 = sp[lane], s1 = sp[lane + 64], s2 = sp[lane + 128], s3 = sp[lane + 192];
    const int4 d0 = dp[lane], d1 = dp[lane + 64], d2 = dp[lane + 128], d3 = dp[lane + 192];

    // ext row (lanes 0..31)
    float er0 = 0.f, er1 = 0.f, er2 = 0.f;
    if (lane < NK) {
        const float* ep = extx + (size_t)g * (NK * 3) + lane * 3;
        er0 = ep[0]; er1 = ep[1]; er2 = ep[2];
    }

    // ---- zero A (2176 dwords/wave, conflict-free) -------------------------
    unsigned* Aw = &A[w * AWDW];
    #pragma unroll
    for (int i = 0; i < 34; ++i) {
        const int idx = i * 64 + lane;
        if (idx < AWDW) Aw[idx] = 0u;
    }

    __builtin_amdgcn_wave_barrier();   // DS ops in-order per wave

    // ---- build adjacency counts: ONE no-return ds_add_u32 per edge --------
    #define SCAT(SV, DV)                                                    \
        {                                                                   \
            const unsigned off = (unsigned)(size_t)&Aw[(DV) * RSTR + ((SV) >> 3)]; \
            const unsigned val = 1u << (4 * ((SV) & 7));                    \
            asm volatile("ds_add_u32 %0, %1" :: "v"(off), "v"(val) : "memory"); \
        }
    SCAT(s0.x, d0.x) SCAT(s0.y, d0.y) SCAT(s0.z, d0.z) SCAT(s0.w, d0.w)
    SCAT(s1.x, d1.x) SCAT(s1.y, d1.y) SCAT(s1.z, d1.z) SCAT(s1.w, d1.w)
    SCAT(s2.x, d2.x) SCAT(s2.y, d2.y) SCAT(s2.z, d2.z) SCAT(s2.w, d2.w)
    SCAT(s3.x, d3.x) SCAT(s3.y, d3.y) SCAT(s3.z, d3.z) SCAT(s3.w, d3.w)
    #undef SCAT

    // drain the scatter before reading A (asm hid the dependency)
    asm volatile("s_waitcnt lgkmcnt(0)" ::: "memory");
    __builtin_amdgcn_wave_barrier();

    // ---- agg = A @ x : lane owns dst rows {lane, lane+64}, agg in regs ----
    float ac0 = 0.f, ac1 = 0.f, ac2 = 0.f;   // node lane
    float ac3 = 0.f, ac4 = 0.f, ac5 = 0.f;   // node lane+64
    const int r0 = lane * RSTR;
    const int r1 = (lane + 64) * RSTR;

    #pragma unroll
    for (int j = 0; j < 16; ++j) {
        const unsigned da = Aw[r0 + j];
        const unsigned db = Aw[r1 + j];
        // x for srcs j*8 .. j*8+7 : 24 floats, same address for all lanes (L1 broadcast)
        float q[24];
        *(float4*)&q[0]  = *(const float4*)(xg + j * 24);
        *(float4*)&q[4]  = *(const float4*)(xg + j * 24 + 4);
        *(float4*)&q[8]  = *(const float4*)(xg + j * 24 + 8);
        *(float4*)&q[12] = *(const float4*)(xg + j * 24 + 12);
        *(float4*)&q[16] = *(const float4*)(xg + j * 24 + 16);
        *(float4*)&q[20] = *(const float4*)(xg + j * 24 + 20);
        #pragma unroll
        for (int o = 0; o < 8; ++o) {
            const float ca = (float)((da >> (4 * o)) & 15u);
            const float cb = (float)((db >> (4 * o)) & 15u);
            const float xs0 = q[o * 3], xs1 = q[o * 3 + 1], xs2 = q[o * 3 + 2];
            ac0 += ca * xs0; ac1 += ca * xs1; ac2 += ca * xs2;
            ac3 += cb * xs0; ac4 += cb * xs1; ac5 += cb * xs2;
        }
    }

    // ---- per-node h = relu(xW + aggM) for the 2 owned nodes ---------------
    float h0, h1, h2;
    {
        const float* xr = xg + lane * 3;
        const float x0 = xr[0], x1 = xr[1], x2 = xr[2];
        h0 = fmaxf(x0 * W[0] + x1 * W[3] + x2 * W[6] +
                   ac0 * M[0] + ac1 * M[3] + ac2 * M[6], 0.f);
        h1 = fmaxf(x0 * W[1] + x1 * W[4] + x2 * W[7] +
                   ac0 * M[1] + ac1 * M[4] + ac2 * M[7], 0.f);
        h2 = fmaxf(x0 * W[2] + x1 * W[5] + x2 * W[8] +
                   ac0 * M[2] + ac1 * M[5] + ac2 * M[8], 0.f);
    }
    {
        const float* xr = xg + (lane + 64) * 3;
        const float x0 = xr[0], x1 = xr[1], x2 = xr[2];
        h0 += fmaxf(x0 * W[0] + x1 * W[3] + x2 * W[6] +
                    ac3 * M[0] + ac4 * M[3] + ac5 * M[6], 0.f);
        h1 += fmaxf(x0 * W[1] + x1 * W[4] + x2 * W[7] +
                    ac3 * M[1] + ac4 * M[4] + ac5 * M[7], 0.f);
        h2 += fmaxf(x0 * W[2] + x1 * W[5] + x2 * W[8] +
                    ac3 * M[2] + ac4 * M[5] + ac5 * M[8], 0.f);
    }

    // ---- reduce within 32-lane halves, combine halves via readlane --------
    #pragma unroll
    for (int off = 16; off > 0; off >>= 1) {
        h0  += __shfl_xor(h0,  off);
        h1  += __shfl_xor(h1,  off);
        h2  += __shfl_xor(h2,  off);
        er0 += __shfl_xor(er0, off);
        er1 += __shfl_xor(er1, off);
        er2 += __shfl_xor(er2, off);
    }
    #define RL(v) (__uint_as_float(__builtin_amdgcn_readlane(__float_as_uint(v), 0)) + \
                   __uint_as_float(__builtin_amdgcn_readlane(__float_as_uint(v), 32)))
    const float H0 = RL(h0), H1 = RL(h1), H2 = RL(h2);
    const float E0 = RL(er0), E1 = RL(er1), E2 = RL(er2);
    #undef RL

    // ---- per-wave tail: emb softmax -> ext MLP -> g_emb -------------------
    if (lane == 0) {
        const float mx = fmaxf(H0, fmaxf(H1, H2));
        const float e0 = __expf(H0 - mx), e1 = __expf(H1 - mx), e2 = __expf(H2 - mx);
        const float inv = 1.0f / (e0 + e1 + e2);
        const float emb0 = e0 * inv, emb1 = e1 * inv, emb2 = e2 * inv;

        float ext[3];
        #pragma unroll
        for (int e = 0; e < 3; ++e) {
            const float vv = emb0 * U[e] + emb1 * U[3 + e] + emb2 * U[6 + e]
                           + E0   * V[e] + E1   * V[3 + e] + E2   * V[6 + e];
            ext[e] = fmaxf(vv, 0.f);
        }
        const float mx2 = fmaxf(ext[0], fmaxf(ext[1], ext[2]));
        const float f0 = __expf(ext[0] - mx2), f1 = __expf(ext[1] - mx2), f2 = __expf(ext[2] - mx2);
        const float inv2 = 1.0f / (f0 + f1 + f2);
        ge[w][0] = f0 * inv2; ge[w][1] = f1 * inv2; ge[w][2] = f2 * inv2;
    }

    __syncthreads();

    // ---- pair combine on lane 0 of waves 0 and 2 --------------------------
    if ((w & 1) == 0 && lane == 0) {
        float tt[6];
        tt[0] = ge[w][0] * ge[w + 1][0];
        tt[1] = ge[w][1] * ge[w + 1][1];
        tt[2] = ge[w][2] * ge[w + 1][2];
        tt[3] = ge[w][0] + ge[w + 1][0];
        tt[4] = ge[w][1] + ge[w + 1][1];
        tt[5] = ge[w][2] + ge[w + 1][2];

        float hl[3];
        #pragma unroll
        for (int j = 0; j < 3; ++j) {
            float vv = b1[j];
            #pragma unroll
            for (int i = 0; i < 6; ++i) vv += tt[i] * W1[i * 3 + j];
            hl[j] = fmaxf(vv, 0.f);
        }

        const float l0 = b2[0] + hl[0] * W2[0] + hl[1] * W2[2] + hl[2] * W2[4];
        const float l1 = b2[1] + hl[0] * W2[1] + hl[1] * W2[3] + hl[2] * W2[5];
        const float mm = fmaxf(l0, l1);
        const float q0 = __expf(l0 - mm), q1 = __expf(l1 - mm);
        const float qi = 1.0f / (q0 + q1);
        out[(size_t)pair * 2    ] = q0 * qi;
        out[(size_t)pair * 2 + 1] = q1 * qi;
    }
}

extern "C" void kernel_launch(void* const* d_in, const int* in_sizes, int n_in,
                              void* d_out, int out_size, void* d_ws, size_t ws_size,
                              hipStream_t stream) {
    const float* x    = (const float*)d_in[0];
    const int*   esrc = (const int*)  d_in[1];
    const int*   edst = (const int*)  d_in[2];
    const float* extx = (const float*)d_in[3];
    const float* W    = (const float*)d_in[4];
    const float* M    = (const float*)d_in[5];
    const float* U    = (const float*)d_in[6];
    const float* V    = (const float*)d_in[7];
    const float* W1   = (const float*)d_in[8];
    const float* b1   = (const float*)d_in[9];
    const float* W2   = (const float*)d_in[10];
    const float* b2   = (const float*)d_in[11];
    float* out = (float*)d_out;

    dcnn_adj_kernel<<<NB / 2, 256, 0, stream>>>(
        x, esrc, edst, extx, W, M, U, V, W1, b1, W2, b2, out);
}